// Round 17
// baseline (60.935 us; speedup 1.0000x reference)
//
#include <hip/hip_runtime.h>
#include <cmath>

#define BB 4
#define TT 8192
#define DD 1024
#define DBLK 8               // d's per block (chain width)
#define NDB (DD/DBLK)        // 128 d-blocks
#define NCHAIN (BB*NDB)      // 512 chains == 512 blocks == 2 per CU
#define CL 512               // timesteps per chunk
#define NITER (TT/CL)        // 16 chunks, carry in registers
#define NTHR 256             // 4 waves
#define NPART (NTHR/DBLK)    // 32 t-parts
#define PLEN (CL/NPART)      // 16 steps per part

// y[b,t,d] = Re(h[t]),  h[t] = r*h[t-1] + x[t],  r = exp(-|a_d|) * cis(w_d)
//
// R16 (50.7us) = persistent chains, no lookback, counted-vmcnt pipeline,
// but 1 block/CU -> HBM idles during scan/stitch. This round: DBLK=8 ->
// 512 blocks = 2 independent blocks/CU; their phases drift -> one block's
// stores/prefetch cover the other's scan/stitch.
// LDS swizzle (rule #21, both-sides-or-neither): global_load_lds writes
// linearly, so we pre-swizzle the per-lane GLOBAL source at 16B-unit
// granularity (unit' = unit ^ (((unit>>5)&3)<<1)) and apply the matching
// float-level XOR on reads (idx ^ ((part&3)<<3)) -> scan conflicts <=2-way
// (free) instead of 8-way.
// XCD swizzle: chain = (bid&7)*64 + bid>>3 -> each XCD owns 64 contiguous
// chains; sibling chains' 32B store granules merge to 128B lines in the
// shared per-XCD L2 (R16 verified the merge at 64B: WRITE was exact).

__global__ __launch_bounds__(NTHR, 2) void fftconv_persist(
    const float* __restrict__ x, const float* __restrict__ decay,
    const float* __restrict__ freq, float* __restrict__ y)
{
    __shared__ float  tile[2][CL*DBLK];    // 32 KB (double buffer)
    __shared__ float2 Ssub[NPART][DBLK];   // 2 KB  per-part sub-aggregates
    __shared__ float2 eoff[NPART][DBLK];   // 2 KB  exclusive in-chunk offsets
    __shared__ float2 HB[DBLK];            // 64 B  carry broadcast

    const int tid  = threadIdx.x;
    const int l8   = tid & 7;              // d-lane
    const int part = tid >> 3;             // 0..31 (t-part)
    const int wv   = tid >> 6;             // wave 0..3
    const int wl   = tid & 63;             // lane in wave
    const int bid  = blockIdx.x;
    // XCD swizzle: 64 contiguous chains per XCD
    const int chain = (bid & 7)*64 + (bid >> 3);
    const int dblk  = chain & (NDB-1);
    const int b     = chain >> 7;          // NDB=128
    const int d     = dblk*DBLK + l8;

    // per-d constants (once per block, reused for 16 chunks)
    const float a = fabsf(decay[d]);
    const float w = freq[d];
    float s_, c_, e;
    e = expf(-a);                    sincosf(w, &s_, &c_);
    const float rr = e*c_, ri = e*s_;                         // r
    e = expf(-a*(float)PLEN);        sincosf(w*(float)PLEN, &s_, &c_);
    const float Msr = e*c_, Msi = e*s_;                       // r^16 (part step)
    e = expf(-a*(float)CL);          sincosf(w*(float)CL, &s_, &c_);
    const float Mcr = e*c_, Mci = e*s_;                       // r^512 (chunk step)
    e = expf(-a*(float)(PLEN*part)); sincosf(w*(float)(PLEN*part), &s_, &c_);
    const float Mpr = e*c_, Mpi = e*s_;                       // r^(16*part)

    const float* xch = x + (size_t)b*TT*DD + dblk*DBLK;
    float*       ych = y + (size_t)b*TT*DD + dblk*DBLK;

    // stage chunk k into tile[buf]: 4 gload_lds x 16B per wave, source
    // pre-swizzled so reads can be bank-despread (see header comment).
    auto stage = [&](int k, int buf) {
        const float* xc = xch + (size_t)(k*CL)*DD;
#pragma unroll
        for (int i = 0; i < 4; ++i) {
            const int base_u = wv*256 + i*64;          // 16B units
            const int uidx   = base_u + wl;
            const int usrc   = uidx ^ (((uidx >> 5) & 3) << 1);
            __builtin_amdgcn_global_load_lds(
                (const __attribute__((address_space(1))) void*)
                    (xc + (size_t)(usrc >> 1)*DD + ((usrc & 1) << 2)),
                (__attribute__((address_space(3))) void*)&tile[buf][base_u << 2],
                16, 0, 0);
        }
    };

    float Hr = 0.f, Hi = 0.f;              // chain carry (valid in tid<8)
    const int cxor = (part & 3) << 3;      // read-side swizzle (float idx)

    stage(0, 0);                           // prologue
    asm volatile("s_waitcnt vmcnt(0)" ::: "memory");
    __builtin_amdgcn_s_barrier();
    __builtin_amdgcn_sched_barrier(0);

    for (int k = 0; k < NITER; ++k) {
        const int cur = k & 1;

        // ---- scan from zero; real-part history in registers ----
        float hRr[PLEN];
        {
            float hr = 0.f, hi = 0.f;
            const int rowbase = part*PLEN*DBLK;        // part*128
#pragma unroll
            for (int t = 0; t < PLEN; ++t) {
                float xv = tile[cur][(rowbase + (t << 3) + l8) ^ cxor];
                float nr = fmaf(rr, hr, fmaf(-ri, hi, xv));
                hi = fmaf(rr, hi, ri*hr);
                hr = nr;
                hRr[t] = hr;
            }
            Ssub[part][l8] = make_float2(hr, hi);
        }
        asm volatile("s_waitcnt lgkmcnt(0)" ::: "memory");
        __builtin_amdgcn_s_barrier();                  // B2: Ssub visible
        __builtin_amdgcn_sched_barrier(0);

        // ---- prefetch next chunk (loads fly under stitch+finish) ----
        if (k + 1 < NITER) stage(k + 1, cur ^ 1);

        // ---- stitch (8 lanes): exclusive offsets + carry update ----
        if (tid < DBLK) {
            float Lr = 0.f, Li = 0.f;
#pragma unroll
            for (int p = 0; p < NPART; ++p) {
                eoff[p][l8] = make_float2(Lr, Li);
                float2 Sp = Ssub[p][l8];
                float nr = fmaf(Msr, Lr, fmaf(-Msi, Li, Sp.x));
                Li = fmaf(Msr, Li, fmaf(Msi, Lr, Sp.y));
                Lr = nr;
            }
            HB[l8] = make_float2(Hr, Hi);   // carry INTO this chunk
            // H = A + Mc*H
            float nHr = fmaf(Mcr, Hr, fmaf(-Mci, Hi, Lr));
            Hi = fmaf(Mcr, Hi, fmaf(Mci, Hr, Li));
            Hr = nHr;
        }
        asm volatile("s_waitcnt lgkmcnt(0)" ::: "memory");
        __builtin_amdgcn_s_barrier();                  // B3: eoff/HB visible
        __builtin_amdgcn_sched_barrier(0);

        // ---- finish: S = eoff + r^(16*part)*H_in; y[t] = hRr[t] + Re(r^(t+1) S) ----
        {
            float2 Hp = HB[l8];
            float2 eo = eoff[part][l8];
            float Sr = eo.x + (Mpr*Hp.x - Mpi*Hp.y);
            float Si = eo.y + (Mpr*Hp.y + Mpi*Hp.x);
            float wr = rr*Sr - ri*Si;      // w = r * S
            float wi = rr*Si + ri*Sr;
            float* yp = ych + (size_t)(k*CL + part*PLEN)*DD + l8;
#pragma unroll
            for (int t = 0; t < PLEN; ++t) {
                yp[(size_t)t*DD] = hRr[t] + wr;   // plain store: L2 line-merge
                float nwr = rr*wr - ri*wi;        // w *= r
                wi = rr*wi + ri*wr;
                wr = nwr;
            }
        }

        // ---- counted wait: 4 stage loads (oldest) done; 16 y-stores fly ----
        if (k + 1 < NITER) {
            asm volatile("s_waitcnt vmcnt(16)" ::: "memory");
            __builtin_amdgcn_s_barrier();              // B1: tile[nxt] ready
            __builtin_amdgcn_sched_barrier(0);
        }
    }
}

extern "C" void kernel_launch(void* const* d_in, const int* in_sizes, int n_in,
                              void* d_out, int out_size, void* d_ws, size_t ws_size,
                              hipStream_t stream) {
    const float* x     = (const float*)d_in[0];
    const float* decay = (const float*)d_in[1];
    const float* freq  = (const float*)d_in[2];
    float*       y     = (float*)d_out;

    // single dispatch; no workspace, no flags, no memset
    fftconv_persist<<<NCHAIN, NTHR, 0, stream>>>(x, decay, freq, y);
}

// Round 18
// 53.814 us; speedup vs baseline: 1.1323x; 1.1323x over previous
//
#include <hip/hip_runtime.h>
#include <cmath>

#define BB 4
#define TT 8192
#define DD 1024
#define DBLK 16              // d's per block: 64B store granule (R16-proven exact)
#define NDB (DD/DBLK)        // 64 d-blocks
#define NCHAIN (BB*NDB)      // 256 chains == 256 blocks == 1 per CU
#define CL 512               // timesteps per chunk
#define NITER (TT/CL)        // 16 chunks, carry in registers
#define NTHR 512             // 8 waves
#define NPART (NTHR/DBLK)    // 32 t-parts
#define PLEN (CL/NPART)      // 16 steps per part
#define NBUF 3               // LDS ring buffers, prefetch depth 2

// y[b,t,d] = Re(h[t]),  h[t] = r*h[t-1] + x[t],  r = exp(-|a_d|) * cis(w_d)
//
// R16 (50.7us, best) = persistent chains, no lookback, counted-vmcnt dbuf.
// R17 lessons: DBLK=8 -> 32B granule write-amplification (keep DBLK=16);
//              both-sides XOR swizzle kills scan bank conflicts (keep).
// This round, on R16's geometry:
//  1) scan-read swizzle (4-way -> 2-way = free): stage SOURCE unit
//     u^(((u>>6)&1)<<2), read float (f)^((part&1)<<4)  [rule #21]
//  2) stage issued at LOOP TOP (target buffer freed one barrier-generation
//     ago) -> loads in flight during scan as well
//  3) 3-buffer ring, depth-2 prefetch, FIFO-counted vmcnt(40/36/32)
//     (never 0 in the loop; m135 FIFO semantics)

__global__ __launch_bounds__(NTHR, 2) void fftconv_persist(
    const float* __restrict__ x, const float* __restrict__ decay,
    const float* __restrict__ freq, float* __restrict__ y)
{
    __shared__ float  tile[NBUF][CL*DBLK]; // 3 x 32 KB
    __shared__ float2 Ssub[NPART][DBLK];   // 4 KB  per-part sub-aggregates
    __shared__ float2 eoff[NPART][DBLK];   // 4 KB  exclusive in-chunk offsets
    __shared__ float2 HB[DBLK];            // 128 B carry broadcast

    const int tid  = threadIdx.x;
    const int l16  = tid & 15;             // d-lane
    const int part = tid >> 4;             // 0..31 (t-part)
    const int wv   = tid >> 6;             // wave 0..7
    const int wl   = tid & 63;             // lane in wave
    const int bid  = blockIdx.x;
    // XCD-pairing swizzle (R16-proven): 32 contiguous chains per XCD
    const int chain = (bid & 7)*32 + (bid >> 3);
    const int dblk  = chain & (NDB-1);
    const int b     = chain >> 6;          // NDB=64
    const int d     = dblk*DBLK + l16;

    // per-d constants (once per block, reused for all 16 chunks)
    const float a = fabsf(decay[d]);
    const float w = freq[d];
    float s_, c_, e;
    e = expf(-a);                    sincosf(w, &s_, &c_);
    const float rr = e*c_, ri = e*s_;                         // r
    e = expf(-a*(float)PLEN);        sincosf(w*(float)PLEN, &s_, &c_);
    const float Msr = e*c_, Msi = e*s_;                       // r^16 (part step)
    e = expf(-a*(float)CL);          sincosf(w*(float)CL, &s_, &c_);
    const float Mcr = e*c_, Mci = e*s_;                       // r^512 (chunk step)
    e = expf(-a*(float)(PLEN*part)); sincosf(w*(float)(PLEN*part), &s_, &c_);
    const float Mpr = e*c_, Mpi = e*s_;                       // r^(16*part)

    const float* xch = x + (size_t)b*TT*DD + dblk*DBLK;
    float*       ych = y + (size_t)b*TT*DD + dblk*DBLK;

    // stage chunk k into tile[buf]: 4 gload_lds x 16B per wave.
    // LDS dest linear (HW rule); SOURCE pre-swizzled so the scan read's
    // matching XOR is bank-despread (both-sides-or-neither, rule #21).
    auto stage = [&](int k, int buf) {
        const float* xc = xch + (size_t)(k*CL)*DD;
#pragma unroll
        for (int i = 0; i < 4; ++i) {
            const int u0 = (wv*4 + i)*64;                  // physical 16B-unit base
            const int up = u0 + wl;
            const int ul = up ^ (((up >> 6) & 1) << 2);    // logical unit
            __builtin_amdgcn_global_load_lds(
                (const __attribute__((address_space(1))) void*)
                    (xc + (size_t)(ul >> 2)*DD + ((ul & 3) << 2)),
                (__attribute__((address_space(3))) void*)&tile[buf][u0 << 2],
                16, 0, 0);
        }
    };

    float Hr = 0.f, Hi = 0.f;              // chain carry (valid in tid<16)
    const int cxor = (part & 1) << 4;      // read-side swizzle (float idx)

    // prologue: fill buffers 0 and 1
    stage(0, 0);
    stage(1, 1);
    asm volatile("s_waitcnt vmcnt(4)" ::: "memory");   // stage(0) retired
    __builtin_amdgcn_s_barrier();
    __builtin_amdgcn_sched_barrier(0);

    for (int k = 0; k < NITER; ++k) {
        const int cur = k % 3;

        // ---- issue stage(k+2) (buffer scanned at iter k-1: free) ----
        if (k + 2 < NITER) stage(k + 2, (k + 2) % 3);

        // ---- FIFO-counted wait: stage(k)'s 4 loads retired ----
        // ops issued after stage(k): stores(k-2) 16 + stage(k+1) 4 +
        // stores(k-1) 16 + stage(k+2) 4 = 40 (36/32 near the tail)
        if (k > 0) {
            if (k <= NITER-3)      asm volatile("s_waitcnt vmcnt(40)" ::: "memory");
            else if (k == NITER-2) asm volatile("s_waitcnt vmcnt(36)" ::: "memory");
            else                   asm volatile("s_waitcnt vmcnt(32)" ::: "memory");
            __builtin_amdgcn_s_barrier();              // tile[cur] ready (all waves)
            __builtin_amdgcn_sched_barrier(0);
        }

        // ---- scan from zero; real-part history in registers ----
        float hRr[PLEN];
        {
            float hr = 0.f, hi = 0.f;
            const int fbase = part*(PLEN*DBLK);        // part*256
#pragma unroll
            for (int t = 0; t < PLEN; ++t) {
                float xv = tile[cur][(fbase + (t << 4) + l16) ^ cxor];
                float nr = fmaf(rr, hr, fmaf(-ri, hi, xv));
                hi = fmaf(rr, hi, ri*hr);
                hr = nr;
                hRr[t] = hr;
            }
            Ssub[part][l16] = make_float2(hr, hi);
        }
        asm volatile("s_waitcnt lgkmcnt(0)" ::: "memory");
        __builtin_amdgcn_s_barrier();                  // B2: Ssub visible
        __builtin_amdgcn_sched_barrier(0);

        // ---- stitch (16 lanes): exclusive offsets + carry update ----
        if (tid < DBLK) {
            float Lr = 0.f, Li = 0.f;
#pragma unroll
            for (int p = 0; p < NPART; ++p) {
                eoff[p][l16] = make_float2(Lr, Li);
                float2 Sp = Ssub[p][l16];
                float nr = fmaf(Msr, Lr, fmaf(-Msi, Li, Sp.x));
                Li = fmaf(Msr, Li, fmaf(Msi, Lr, Sp.y));
                Lr = nr;
            }
            HB[l16] = make_float2(Hr, Hi);  // carry INTO this chunk
            // H = A + Mc*H
            float nHr = fmaf(Mcr, Hr, fmaf(-Mci, Hi, Lr));
            Hi = fmaf(Mcr, Hi, fmaf(Mci, Hr, Li));
            Hr = nHr;
        }
        asm volatile("s_waitcnt lgkmcnt(0)" ::: "memory");
        __builtin_amdgcn_s_barrier();                  // B3: eoff/HB visible
        __builtin_amdgcn_sched_barrier(0);

        // ---- finish: S = eoff + r^(16*part)*H_in; y[t] = hRr[t] + Re(r^(t+1) S) ----
        {
            float2 Hp = HB[l16];
            float2 eo = eoff[part][l16];
            float Sr = eo.x + (Mpr*Hp.x - Mpi*Hp.y);
            float Si = eo.y + (Mpr*Hp.y + Mpi*Hp.x);
            float wr = rr*Sr - ri*Si;      // w = r * S
            float wi = rr*Si + ri*Sr;
            float* yp = ych + (size_t)(k*CL + part*PLEN)*DD + l16;
#pragma unroll
            for (int t = 0; t < PLEN; ++t) {
                yp[(size_t)t*DD] = hRr[t] + wr;   // plain store: 64B L2 granule
                float nwr = rr*wr - ri*wi;        // w *= r
                wi = rr*wi + ri*wr;
                wr = nwr;
            }
        }
        // no wait here: stores drain under the next iteration's scan
    }
}

extern "C" void kernel_launch(void* const* d_in, const int* in_sizes, int n_in,
                              void* d_out, int out_size, void* d_ws, size_t ws_size,
                              hipStream_t stream) {
    const float* x     = (const float*)d_in[0];
    const float* decay = (const float*)d_in[1];
    const float* freq  = (const float*)d_in[2];
    float*       y     = (float*)d_out;

    // single dispatch; no workspace, no flags, no memset
    fftconv_persist<<<NCHAIN, NTHR, 0, stream>>>(x, decay, freq, y);
}

// Round 19
// 51.751 us; speedup vs baseline: 1.1775x; 1.0399x over previous
//
#include <hip/hip_runtime.h>
#include <cmath>

#define BB 4
#define TT 8192
#define DD 1024
#define DBLK 16              // d's per block: 64B store granule (R16-proven exact)
#define NDB (DD/DBLK)        // 64 d-blocks
#define NCHAIN (BB*NDB)      // 256 chains == 256 blocks == 1 per CU
#define CL 1024              // timesteps per chunk (R16 geometry)
#define NITER (TT/CL)        // 8 chunks, carry in registers
#define NTHR 512             // 8 waves
#define NPART (NTHR/DBLK)    // 32 t-parts
#define PLEN (CL/NPART)      // 32 steps per part

// y[b,t,d] = Re(h[t]),  h[t] = r*h[t-1] + x[t],  r = exp(-|a_d|) * cis(w_d)
//
// R19 = R16 (50.7us, best) + exactly two proven-free fixes:
//  1) both-sides XOR swizzle (R18: conflicts 1.05M -> 0): logical float L
//     lives at physical P = L ^ (((L>>9)&1)<<4). Stage pre-swizzles the
//     GLOBAL source unit (u ^ (((u>>7)&1)<<2)); scan reads f ^ ((part&1)<<4).
//     4-way -> 2-way (free) on the scan.
//  2) stage(k+1) issued at LOOP TOP (R18 counting): target buffer was
//     scanned at iter k-1, freed by its barrier. FIFO-counted waits:
//     vmcnt(8) iter0, vmcnt(40) middle (32 stores + 8 loads younger than
//     stage(k)), vmcnt(32) last. Loads in flight during the scan.
// Everything else identical to R16: persistent chains, register carry,
// no lookback/flags/memset, raw s_barrier, plain 64B-granule y stores,
// XCD-pairing chain swizzle.

__global__ __launch_bounds__(NTHR, 2) void fftconv_persist(
    const float* __restrict__ x, const float* __restrict__ decay,
    const float* __restrict__ freq, float* __restrict__ y)
{
    __shared__ float  tile[2][CL*DBLK];    // 128 KB (double buffer)
    __shared__ float2 Ssub[NPART][DBLK];   // 4 KB  per-part sub-aggregates
    __shared__ float2 eoff[NPART][DBLK];   // 4 KB  exclusive in-chunk offsets
    __shared__ float2 HB[DBLK];            // 128 B carry broadcast

    const int tid  = threadIdx.x;
    const int l16  = tid & 15;             // d-lane
    const int part = tid >> 4;             // 0..31 (t-part)
    const int wv   = tid >> 6;             // wave 0..7
    const int wl   = tid & 63;             // lane in wave
    const int bid  = blockIdx.x;
    // XCD-pairing swizzle (R16-proven): 32 contiguous chains per XCD
    const int chain = (bid & 7)*32 + (bid >> 3);
    const int dblk  = chain & (NDB-1);
    const int b     = chain >> 6;          // NDB=64
    const int d     = dblk*DBLK + l16;

    // per-d constants (once per block, reused for 8 chunks)
    const float a = fabsf(decay[d]);
    const float w = freq[d];
    float s_, c_, e;
    e = expf(-a);                    sincosf(w, &s_, &c_);
    const float rr = e*c_, ri = e*s_;                         // r
    e = expf(-a*(float)PLEN);        sincosf(w*(float)PLEN, &s_, &c_);
    const float Msr = e*c_, Msi = e*s_;                       // r^32  (part step)
    e = expf(-a*(float)CL);          sincosf(w*(float)CL, &s_, &c_);
    const float Mcr = e*c_, Mci = e*s_;                       // r^1024 (chunk step)
    e = expf(-a*(float)(PLEN*part)); sincosf(w*(float)(PLEN*part), &s_, &c_);
    const float Mpr = e*c_, Mpi = e*s_;                       // r^(32*part)

    const float* xch = x + (size_t)b*TT*DD + dblk*DBLK;
    float*       ych = y + (size_t)b*TT*DD + dblk*DBLK;

    // stage chunk k into tile[buf]: 8 gload_lds x 16B per wave.
    // LDS dest linear (HW rule: wave base + lane*16B); GLOBAL source
    // pre-swizzled with the involution u ^ (((u>>7)&1)<<2) so the scan's
    // read-side XOR lands on the right data (both-sides-or-neither).
    auto stage = [&](int k, int buf) {
        const float* xc = xch + (size_t)(k*CL)*DD;
#pragma unroll
        for (int i = 0; i < 8; ++i) {
            const int u0 = (wv*8 + i)*64;                  // physical 16B-unit base
            const int up = u0 + wl;
            const int ul = up ^ (((up >> 7) & 1) << 2);    // logical unit (involution)
            __builtin_amdgcn_global_load_lds(
                (const __attribute__((address_space(1))) void*)
                    (xc + (size_t)(ul >> 2)*DD + ((ul & 3) << 2)),
                (__attribute__((address_space(3))) void*)&tile[buf][u0 << 2],
                16, 0, 0);
        }
    };

    float Hr = 0.f, Hi = 0.f;              // chain carry (valid in tid<16)
    const int cxor = (part & 1) << 4;      // read-side swizzle (float idx)

    stage(0, 0);                           // prologue: iteration 0's tile

    for (int k = 0; k < NITER; ++k) {
        const int cur = k & 1;

        // ---- issue next stage first: loads fly during this scan ----
        if (k + 1 < NITER) stage(k + 1, cur ^ 1);

        // ---- FIFO-counted wait: stage(k)'s 8 loads retired ----
        if (k == 0)                asm volatile("s_waitcnt vmcnt(8)"  ::: "memory");
        else if (k + 1 < NITER)    asm volatile("s_waitcnt vmcnt(40)" ::: "memory");
        else                       asm volatile("s_waitcnt vmcnt(32)" ::: "memory");
        __builtin_amdgcn_s_barrier();                  // tile[cur] ready (all waves)
        __builtin_amdgcn_sched_barrier(0);

        // ---- scan from zero; real-part history in registers ----
        float hRr[PLEN];
        {
            float hr = 0.f, hi = 0.f;
            const int fbase = part << 9;               // part*512 floats
#pragma unroll
            for (int t = 0; t < PLEN; ++t) {
                float xv = tile[cur][(fbase + (t << 4) + l16) ^ cxor];
                float nr = fmaf(rr, hr, fmaf(-ri, hi, xv));
                hi = fmaf(rr, hi, ri*hr);
                hr = nr;
                hRr[t] = hr;
            }
            Ssub[part][l16] = make_float2(hr, hi);
        }
        asm volatile("s_waitcnt lgkmcnt(0)" ::: "memory");
        __builtin_amdgcn_s_barrier();                  // B2: Ssub visible
        __builtin_amdgcn_sched_barrier(0);

        // ---- stitch (16 lanes): exclusive offsets + carry update ----
        if (tid < DBLK) {
            float Lr = 0.f, Li = 0.f;
#pragma unroll
            for (int p = 0; p < NPART; ++p) {
                eoff[p][l16] = make_float2(Lr, Li);
                float2 Sp = Ssub[p][l16];
                float nr = fmaf(Msr, Lr, fmaf(-Msi, Li, Sp.x));
                Li = fmaf(Msr, Li, fmaf(Msi, Lr, Sp.y));
                Lr = nr;
            }
            HB[l16] = make_float2(Hr, Hi);  // carry INTO this chunk
            // H = A + Mc*H  (A = zero-seeded chunk aggregate)
            float nHr = fmaf(Mcr, Hr, fmaf(-Mci, Hi, Lr));
            Hi = fmaf(Mcr, Hi, fmaf(Mci, Hr, Li));
            Hr = nHr;
        }
        asm volatile("s_waitcnt lgkmcnt(0)" ::: "memory");
        __builtin_amdgcn_s_barrier();                  // B3: eoff/HB visible
        __builtin_amdgcn_sched_barrier(0);

        // ---- finish: S = eoff + r^(32*part)*H_in; y[t] = hRr[t] + Re(r^(t+1) S) ----
        {
            float2 Hp = HB[l16];
            float2 eo = eoff[part][l16];
            float Sr = eo.x + (Mpr*Hp.x - Mpi*Hp.y);
            float Si = eo.y + (Mpr*Hp.y + Mpi*Hp.x);
            float wr = rr*Sr - ri*Si;      // w = r * S
            float wi = rr*Si + ri*Sr;
            float* yp = ych + (size_t)(k*CL + part*PLEN)*DD + l16;
#pragma unroll
            for (int t = 0; t < PLEN; ++t) {
                yp[(size_t)t*DD] = hRr[t] + wr;   // plain store: 64B L2 granule
                float nwr = rr*wr - ri*wi;        // w *= r
                wi = rr*wi + ri*wr;
                wr = nwr;
            }
        }
        // no trailing wait: stores drain under the next iteration's scan
    }
}

extern "C" void kernel_launch(void* const* d_in, const int* in_sizes, int n_in,
                              void* d_out, int out_size, void* d_ws, size_t ws_size,
                              hipStream_t stream) {
    const float* x     = (const float*)d_in[0];
    const float* decay = (const float*)d_in[1];
    const float* freq  = (const float*)d_in[2];
    float*       y     = (float*)d_out;

    // single dispatch; no workspace, no flags, no memset
    fftconv_persist<<<NCHAIN, NTHR, 0, stream>>>(x, decay, freq, y);
}

// Round 20
// 50.829 us; speedup vs baseline: 1.1988x; 1.0181x over previous
//
#include <hip/hip_runtime.h>
#include <cmath>

#define BB 4
#define TT 8192
#define DD 1024
#define DBLK 16              // d's per block: 64B store granule (R16-proven)
#define NDB (DD/DBLK)        // 64 d-blocks
#define NCHAIN (BB*NDB)      // 256 chains == 256 blocks == 1 per CU
#define CL 1024              // timesteps per chunk (R16 geometry)
#define NITER (TT/CL)        // 8 chunks, carry in registers
#define NTHR 1024            // 16 waves (4 per SIMD) -- the change under test
#define NPART (NTHR/DBLK)    // 64 t-parts
#define PLEN (CL/NPART)      // 16 steps per part
#define NGRP 8               // stitch groups (8 parts each)

// y[b,t,d] = Re(h[t]),  h[t] = r*h[t-1] + x[t],  r = exp(-|a_d|) * cis(w_d)
//
// R20 = R16 structure at 16 waves/CU (4/SIMD, was 2/SIMD). R19 showed the
// residue isn't LDS conflicts or load-queue gaps; hypothesis: TLP-starved
// scan (dependent FMA chain) + finish (store issue). Two-level stitch keeps
// serial depth at 8+8 (level2 absorbs the chain carry: E init = H, H = E
// final -- no separate carry step, no HB broadcast).
// Carried over: persistent chains, no lookback/flags/memset, raw s_barrier,
// FIFO-counted vmcnt (never 0 mid-loop), XCD-pairing chain swizzle,
// both-sides XOR bank swizzle (src u^(((u>>6)&1)<<2), read f^((part&1)<<4)).

__global__ __launch_bounds__(NTHR, 1) void fftconv_persist(
    const float* __restrict__ x, const float* __restrict__ decay,
    const float* __restrict__ freq, float* __restrict__ y)
{
    __shared__ float  tile[2][CL*DBLK];    // 128 KB (double buffer)
    __shared__ float2 Ssub[NPART][DBLK];   // 8 KB  per-part sub-aggregates
    __shared__ float2 eoff[NPART][DBLK];   // 8 KB  within-group exclusive offsets
    __shared__ float2 Gs[NGRP][DBLK];      // 1 KB  group aggregates
    __shared__ float2 Eg[NGRP][DBLK];      // 1 KB  group-exclusive state (incl. carry)

    const int tid  = threadIdx.x;
    const int l16  = tid & 15;             // d-lane
    const int part = tid >> 4;             // 0..63 (t-part)
    const int wv   = tid >> 6;             // wave 0..15
    const int wl   = tid & 63;             // lane in wave
    const int bid  = blockIdx.x;
    // XCD-pairing swizzle (R16-proven): 32 contiguous chains per XCD
    const int chain = (bid & 7)*32 + (bid >> 3);
    const int dblk  = chain & (NDB-1);
    const int b     = chain >> 6;          // NDB=64
    const int d     = dblk*DBLK + l16;

    // per-d constants (once per block, reused for 8 chunks)
    const float a = fabsf(decay[d]);
    const float w = freq[d];
    float s_, c_, e;
    e = expf(-a);                     sincosf(w, &s_, &c_);
    const float rr = e*c_, ri = e*s_;                          // r
    e = expf(-a*(float)PLEN);         sincosf(w*(float)PLEN, &s_, &c_);
    const float Msr = e*c_, Msi = e*s_;                        // r^16  (part step)
    e = expf(-a*(float)(PLEN*NGRP));  sincosf(w*(float)(PLEN*NGRP), &s_, &c_);
    const float Mgr = e*c_, Mgi = e*s_;                        // r^128 (group step)
    {
        const float tj = (float)(PLEN*(part & (NGRP-1)));
        e = expf(-a*tj); sincosf(w*tj, &s_, &c_);
    }
    const float Mjr = e*c_, Mji = e*s_;                        // r^(16*(part%8))

    const float* xch = x + (size_t)b*TT*DD + dblk*DBLK;
    float*       ych = y + (size_t)b*TT*DD + dblk*DBLK;

    // stage chunk k into tile[buf]: 4 gload_lds x 16B per wave (16 waves).
    // LDS dest linear (HW rule); GLOBAL source pre-swizzled with the
    // involution u ^ (((u>>6)&1)<<2)  <=>  float f ^ (((f>>8)&1)<<4),
    // matching the scan's read-side XOR (both-sides-or-neither, rule #21).
    auto stage = [&](int k, int buf) {
        const float* xc = xch + (size_t)(k*CL)*DD;
#pragma unroll
        for (int i = 0; i < 4; ++i) {
            const int u0 = (wv*4 + i)*64;                  // physical 16B-unit base
            const int up = u0 + wl;
            const int ul = up ^ (((up >> 6) & 1) << 2);    // logical unit
            __builtin_amdgcn_global_load_lds(
                (const __attribute__((address_space(1))) void*)
                    (xc + (size_t)(ul >> 2)*DD + ((ul & 3) << 2)),
                (__attribute__((address_space(3))) void*)&tile[buf][u0 << 2],
                16, 0, 0);
        }
    };

    float Hr = 0.f, Hi = 0.f;              // chain carry (valid in tid<16)
    const int cxor = (part & 1) << 4;      // read-side swizzle (float idx)

    stage(0, 0);                           // prologue: iteration 0's tile

    for (int k = 0; k < NITER; ++k) {
        const int cur = k & 1;

        // ---- issue next stage first: loads fly during this scan ----
        if (k + 1 < NITER) stage(k + 1, cur ^ 1);

        // ---- FIFO-counted wait: stage(k)'s 4 loads retired ----
        // younger ops: stores(k-1) 16 + stage(k+1) 4 = 20 (16 at tail, 4 at k=0)
        if (k == 0)             asm volatile("s_waitcnt vmcnt(4)"  ::: "memory");
        else if (k + 1 < NITER) asm volatile("s_waitcnt vmcnt(20)" ::: "memory");
        else                    asm volatile("s_waitcnt vmcnt(16)" ::: "memory");
        __builtin_amdgcn_s_barrier();                  // tile[cur] ready (all waves)
        __builtin_amdgcn_sched_barrier(0);

        // ---- scan from zero; real-part history in registers ----
        float hRr[PLEN];
        {
            float hr = 0.f, hi = 0.f;
            const int fbase = part << 8;               // part*256 floats
#pragma unroll
            for (int t = 0; t < PLEN; ++t) {
                float xv = tile[cur][(fbase + (t << 4) + l16) ^ cxor];
                float nr = fmaf(rr, hr, fmaf(-ri, hi, xv));
                hi = fmaf(rr, hi, ri*hr);
                hr = nr;
                hRr[t] = hr;
            }
            Ssub[part][l16] = make_float2(hr, hi);
        }
        asm volatile("s_waitcnt lgkmcnt(0)" ::: "memory");
        __builtin_amdgcn_s_barrier();                  // B2: Ssub visible
        __builtin_amdgcn_sched_barrier(0);

        // ---- stitch level 1 (128 threads): within-group exclusive prefixes ----
        if (tid < NGRP*DBLK) {
            const int sp = tid >> 4;                   // group 0..7
            const int l  = tid & 15;
            float Wr = 0.f, Wi = 0.f;
#pragma unroll
            for (int j = 0; j < NGRP; ++j) {
                const int p = sp*NGRP + j;
                eoff[p][l] = make_float2(Wr, Wi);
                float2 Sp = Ssub[p][l];
                float nr = fmaf(Msr, Wr, fmaf(-Msi, Wi, Sp.x));
                Wi = fmaf(Msr, Wi, fmaf(Msi, Wr, Sp.y));
                Wr = nr;
            }
            Gs[sp][l] = make_float2(Wr, Wi);           // group aggregate
        }
        asm volatile("s_waitcnt lgkmcnt(0)" ::: "memory");
        __builtin_amdgcn_s_barrier();                  // B2b: eoff/Gs visible
        __builtin_amdgcn_sched_barrier(0);

        // ---- stitch level 2 (16 lanes): group scan, carry absorbed ----
        if (tid < DBLK) {
            float Er = Hr, Ei = Hi;                    // E init = carry INTO chunk
#pragma unroll
            for (int g = 0; g < NGRP; ++g) {
                Eg[g][l16] = make_float2(Er, Ei);
                float2 G = Gs[g][l16];
                float nr = fmaf(Mgr, Er, fmaf(-Mgi, Ei, G.x));
                Ei = fmaf(Mgr, Ei, fmaf(Mgi, Er, G.y));
                Er = nr;
            }
            Hr = Er; Hi = Ei;                          // carry OUT of chunk
        }
        asm volatile("s_waitcnt lgkmcnt(0)" ::: "memory");
        __builtin_amdgcn_s_barrier();                  // B3: Eg visible
        __builtin_amdgcn_sched_barrier(0);

        // ---- finish: S = eoff[part] + r^(16*(part%8)) * Eg[part/8] ----
        {
            const int g = part >> 3;
            float2 eo = eoff[part][l16];
            float2 Ev = Eg[g][l16];
            float Sr = eo.x + (Mjr*Ev.x - Mji*Ev.y);
            float Si = eo.y + (Mjr*Ev.y + Mji*Ev.x);
            float wr = rr*Sr - ri*Si;      // w = r * S
            float wi = rr*Si + ri*Sr;
            float* yp = ych + (size_t)(k*CL + part*PLEN)*DD + l16;
#pragma unroll
            for (int t = 0; t < PLEN; ++t) {
                yp[(size_t)t*DD] = hRr[t] + wr;   // plain store: 64B L2 granule
                float nwr = rr*wr - ri*wi;        // w *= r
                wi = rr*wi + ri*wr;
                wr = nwr;
            }
        }
        // no trailing wait: stores drain under the next iteration's scan
    }
}

extern "C" void kernel_launch(void* const* d_in, const int* in_sizes, int n_in,
                              void* d_out, int out_size, void* d_ws, size_t ws_size,
                              hipStream_t stream) {
    const float* x     = (const float*)d_in[0];
    const float* decay = (const float*)d_in[1];
    const float* freq  = (const float*)d_in[2];
    float*       y     = (float*)d_out;

    // single dispatch; no workspace, no flags, no memset
    fftconv_persist<<<NCHAIN, NTHR, 0, stream>>>(x, decay, freq, y);
}